// Round 1
// baseline (331.690 us; speedup 1.0000x reference)
//
#include <hip/hip_runtime.h>
#include <math.h>

// ---------------------------------------------------------------------------
// S5 dual (fwd+bwd) SSM:  B=4, L=4096, H=1024, P=256
// Pipeline:
//   cast_x:  x fp32 -> bf16                                  (for GEMM1 A)
//   prep:    build W [1024x1024] bf16 (B_bar rows, re/im interleaved),
//            CmT [1024x1024] bf16 (C^T with -C_imag), lambda params
//   gemm1:   Z[16384,1024] = xbf @ W^T   (fp32 out)
//   scanA:   per-chunk local complex scans, in place on Z; chunk aggregates
//   scanB:   carry scan across 64 chunks per (b,dir,p) with lambda^64
//   scanC:   xs = local + lambda^i * carry -> bf16 xsbf
//   gemm2:   acc_f/acc_b = xsbf @ CmT^T (K split 512/512);
//            out = gelu(acc_f + Df*x) + gelu(acc_b + Db*x)
// Column layout (inner 1024): c = dir*512 + 2*p + comp  (comp: 0=re, 1=im)
// ---------------------------------------------------------------------------

typedef short bf16x8 __attribute__((ext_vector_type(8)));
typedef float f32x4 __attribute__((ext_vector_type(4)));
typedef unsigned short u16x8 __attribute__((ext_vector_type(8)));

__device__ __forceinline__ unsigned short f2bf(float f) {
  union { float f; unsigned int u; } v; v.f = f;
  unsigned int r = (v.u + 0x7FFFu + ((v.u >> 16) & 1u)) >> 16;
  return (unsigned short)r;
}
__device__ __forceinline__ float bf2f(unsigned short s) {
  union { unsigned int u; float f; } v; v.u = ((unsigned int)s) << 16;
  return v.f;
}
__device__ __forceinline__ float gelu_exact(float v) {
  return 0.5f * v * (1.0f + erff(v * 0.70710678118654752f));
}
__device__ __forceinline__ void gload16(const unsigned short* g, void* l) {
  __builtin_amdgcn_global_load_lds(
      (const __attribute__((address_space(1))) void*)g,
      (__attribute__((address_space(3))) void*)l, 16, 0, 0);
}

// ------------------------------- cast x -> bf16 ----------------------------
__global__ __launch_bounds__(256) void cast_x_kernel(
    const float* __restrict__ x, unsigned short* __restrict__ xbf) {
  const size_t i = (size_t)blockIdx.x * 256 + threadIdx.x;  // 2,097,152 total
  const float4* xv = (const float4*)x;
  float4 a = xv[2 * i], b = xv[2 * i + 1];
  u16x8 r;
  r[0] = f2bf(a.x); r[1] = f2bf(a.y); r[2] = f2bf(a.z); r[3] = f2bf(a.w);
  r[4] = f2bf(b.x); r[5] = f2bf(b.y); r[6] = f2bf(b.z); r[7] = f2bf(b.w);
  *(u16x8*)(xbf + 8 * i) = r;
}

// ------------------------------- prep ---------------------------------------
__global__ __launch_bounds__(256) void prep_kernel(
    const float* __restrict__ flr, const float* __restrict__ fim,
    const float* __restrict__ fBr, const float* __restrict__ fBi,
    const float* __restrict__ fCr, const float* __restrict__ fCi,
    const float* __restrict__ flD,
    const float* __restrict__ blr, const float* __restrict__ bim,
    const float* __restrict__ bBr, const float* __restrict__ bBi,
    const float* __restrict__ bCr, const float* __restrict__ bCi,
    const float* __restrict__ blD,
    unsigned short* __restrict__ W, unsigned short* __restrict__ CmT,
    float4* __restrict__ lamp) {
  const int bid = blockIdx.x, tid = threadIdx.x;
  if (bid < 512) {
    const int dir = bid >> 8, p = bid & 255;
    const float* lr_ = dir ? blr : flr;
    const float* im_ = dir ? bim : fim;
    const float* lD_ = dir ? blD : flD;
    const float* Br_ = dir ? bBr : fBr;
    const float* Bi_ = dir ? bBi : fBi;
    const float Lre = -expf(lr_[p]);
    const float Lim = im_[p];
    const float Dl = expf(lD_[p]);
    const float ar = Lre * Dl, ai = Lim * Dl;
    const float er = expf(ar);
    const float lre = er * cosf(ai), lim = er * sinf(ai);
    const float e64 = expf(64.f * ar);
    const float l64re = e64 * cosf(64.f * ai), l64im = e64 * sinf(64.f * ai);
    float sre = Lre, sim = Lim;
    if (sqrtf(Lre * Lre + Lim * Lim) < 1e-6f) { sre = 1e-6f; sim = 0.f; }
    const float den = sre * sre + sim * sim;
    const float fre = ((lre - 1.f) * sre + lim * sim) / den;
    const float fi2 = (lim * sre - (lre - 1.f) * sim) / den;
    if (tid == 0) lamp[dir * 256 + p] = make_float4(lre, lim, l64re, l64im);
    const size_t rowR = (size_t)(dir * 512 + 2 * p) * 1024;
    const size_t rowI = rowR + 1024;
    for (int h = tid; h < 1024; h += 256) {
      const float Br = Br_[p * 1024 + h], Bi = Bi_[p * 1024 + h];
      W[rowR + h] = f2bf(fre * Br - fi2 * Bi);
      W[rowI + h] = f2bf(fre * Bi + fi2 * Br);
    }
  } else {
    const int h = bid - 512;
    for (int k = tid; k < 1024; k += 256) {
      const int dir = k >> 9, within = k & 511;
      const int p = within >> 1, comp = within & 1;
      const float* C = comp ? (dir ? bCi : fCi) : (dir ? bCr : fCr);
      float v = C[(size_t)h * 256 + p];
      if (comp) v = -v;
      CmT[(size_t)h * 1024 + k] = f2bf(v);
    }
  }
}

// ------------------------------- GEMM1 --------------------------------------
// Z[m][c] = sum_h xbf[m][h] * W[c][h];  M=16384, N=1024, K=1024
__global__ __launch_bounds__(256) void gemm1_kernel(
    const unsigned short* __restrict__ xbf, const unsigned short* __restrict__ W,
    float* __restrict__ Z) {
  __shared__ unsigned short As[128 * 64];
  __shared__ unsigned short Bs[128 * 64];
  const int tid = threadIdx.x;
  const int lane = tid & 63;
  const int w = tid >> 6;
  const int wm = w >> 1, wn = w & 1;
  const int fr = lane & 15;
  const int ks = (lane >> 4) << 3;
  const int nt = blockIdx.x & 7, mt = blockIdx.x >> 3;
  const int m0 = mt << 7, n0 = nt << 7;

  f32x4 acc[4][4] = {};

  for (int kt = 0; kt < 16; ++kt) {
    const int k0 = kt << 6;
#pragma unroll
    for (int i = 0; i < 4; ++i) {
      const int o = (i << 12) + (tid << 4);
      const int r = o >> 7;
      const int c = (o & 127) >> 1;
      gload16(xbf + (size_t)(m0 + r) * 1024 + (k0 + c), (char*)As + o);
      gload16(W + (size_t)(n0 + r) * 1024 + (k0 + c), (char*)Bs + o);
    }
    __syncthreads();
#pragma unroll
    for (int kk = 0; kk < 64; kk += 32) {
      bf16x8 af[4], bf_[4];
#pragma unroll
      for (int m4 = 0; m4 < 4; ++m4)
        af[m4] = *(const bf16x8*)&As[((wm << 6) + (m4 << 4) + fr) * 64 + kk + ks];
#pragma unroll
      for (int n4 = 0; n4 < 4; ++n4)
        bf_[n4] = *(const bf16x8*)&Bs[((wn << 6) + (n4 << 4) + fr) * 64 + kk + ks];
#pragma unroll
      for (int m4 = 0; m4 < 4; ++m4)
#pragma unroll
        for (int n4 = 0; n4 < 4; ++n4)
          acc[m4][n4] = __builtin_amdgcn_mfma_f32_16x16x32_bf16(
              af[m4], bf_[n4], acc[m4][n4], 0, 0, 0);
    }
    __syncthreads();
  }
  const int rb = (lane >> 4) << 2;
#pragma unroll
  for (int m4 = 0; m4 < 4; ++m4)
#pragma unroll
    for (int n4 = 0; n4 < 4; ++n4) {
      const size_t gn = n0 + (wn << 6) + (n4 << 4) + fr;
#pragma unroll
      for (int r = 0; r < 4; ++r) {
        const size_t gm = m0 + (wm << 6) + (m4 << 4) + rb + r;
        Z[gm * 1024 + gn] = acc[m4][n4][r];
      }
    }
}

// ------------------------------- scans --------------------------------------
__global__ __launch_bounds__(256) void scanA_kernel(
    float* __restrict__ Z, const float4* __restrict__ lamp,
    float2* __restrict__ partials) {
  const int p = threadIdx.x;
  const int chunk = blockIdx.x & 63;
  const int dir = (blockIdx.x >> 6) & 1;
  const int b = blockIdx.x >> 7;
  const float4 lp = lamp[dir * 256 + p];
  const float lre = lp.x, lim = lp.y;
  float2* Zv = (float2*)Z;
  const size_t col = (size_t)dir * 256 + p;
  const size_t mbase = (size_t)b * 4096 + (size_t)chunk * 64;
  float sre = 0.f, sim = 0.f;
  if (dir == 0) {
    for (int i = 0; i < 64; ++i) {
      const size_t idx = (mbase + i) * 512 + col;
      float2 u = Zv[idx];
      float nr = fmaf(lre, sre, fmaf(-lim, sim, u.x));
      float ni = fmaf(lre, sim, fmaf(lim, sre, u.y));
      sre = nr; sim = ni;
      Zv[idx] = make_float2(sre, sim);
    }
  } else {
    for (int i = 63; i >= 0; --i) {
      const size_t idx = (mbase + i) * 512 + col;
      float2 u = Zv[idx];
      float nr = fmaf(lre, sre, fmaf(-lim, sim, u.x));
      float ni = fmaf(lre, sim, fmaf(lim, sre, u.y));
      sre = nr; sim = ni;
      Zv[idx] = make_float2(sre, sim);
    }
  }
  partials[((size_t)(b * 2 + dir) * 256 + p) * 64 + chunk] = make_float2(sre, sim);
}

__global__ __launch_bounds__(256) void scanB_kernel(
    const float2* __restrict__ partials, float2* __restrict__ carries,
    const float4* __restrict__ lamp) {
  const int t = blockIdx.x * 256 + threadIdx.x;  // < 2048
  const int p = t & 255;
  const int dir = (t >> 8) & 1;
  const int b = t >> 9;
  const float4 lp = lamp[dir * 256 + p];
  const float ar = lp.z, ai = lp.w;  // lambda^64
  const size_t base = ((size_t)(b * 2 + dir) * 256 + p) * 64;
  float cr = 0.f, ci = 0.f;
  if (dir == 0) {
    for (int c = 0; c < 64; ++c) {
      carries[base + c] = make_float2(cr, ci);
      float2 s = partials[base + c];
      float nr = fmaf(ar, cr, fmaf(-ai, ci, s.x));
      float ni = fmaf(ar, ci, fmaf(ai, cr, s.y));
      cr = nr; ci = ni;
    }
  } else {
    for (int c = 63; c >= 0; --c) {
      carries[base + c] = make_float2(cr, ci);
      float2 s = partials[base + c];
      float nr = fmaf(ar, cr, fmaf(-ai, ci, s.x));
      float ni = fmaf(ar, ci, fmaf(ai, cr, s.y));
      cr = nr; ci = ni;
    }
  }
}

__global__ __launch_bounds__(256) void scanC_kernel(
    const float* __restrict__ Z, const float4* __restrict__ lamp,
    const float2* __restrict__ carries, unsigned int* __restrict__ xsbf) {
  const int p = threadIdx.x;
  const int chunk = blockIdx.x & 63;
  const int dir = (blockIdx.x >> 6) & 1;
  const int b = blockIdx.x >> 7;
  const float4 lp = lamp[dir * 256 + p];
  const float lre = lp.x, lim = lp.y;
  const float2* Zv = (const float2*)Z;
  const size_t col = (size_t)dir * 256 + p;
  const size_t mbase = (size_t)b * 4096 + (size_t)chunk * 64;
  const float2 K = carries[((size_t)(b * 2 + dir) * 256 + p) * 64 + chunk];
  float qr = lre * K.x - lim * K.y;
  float qi = lre * K.y + lim * K.x;
  if (dir == 0) {
    for (int i = 0; i < 64; ++i) {
      const size_t idx = (mbase + i) * 512 + col;
      float2 u = Zv[idx];
      const float vr = u.x + qr, vi = u.y + qi;
      xsbf[idx] = (unsigned int)f2bf(vr) | ((unsigned int)f2bf(vi) << 16);
      const float t2 = lre * qr - lim * qi;
      qi = lre * qi + lim * qr; qr = t2;
    }
  } else {
    for (int i = 63; i >= 0; --i) {
      const size_t idx = (mbase + i) * 512 + col;
      float2 u = Zv[idx];
      const float vr = u.x + qr, vi = u.y + qi;
      xsbf[idx] = (unsigned int)f2bf(vr) | ((unsigned int)f2bf(vi) << 16);
      const float t2 = lre * qr - lim * qi;
      qi = lre * qi + lim * qr; qr = t2;
    }
  }
}

// ------------------------------- GEMM2 + epilogue ---------------------------
// acc_f[m][h] = sum_{k<512} A2[m][k]*CmT[h][k]; acc_b over k in [512,1024)
// out = gelu(acc_f + Df*x) + gelu(acc_b + Db*x)
#define GEMM2_KSTEP(ACC, KT)                                                   \
  {                                                                            \
    const int k0 = (KT) << 6;                                                  \
    _Pragma("unroll") for (int i = 0; i < 4; ++i) {                            \
      const int o = (i << 12) + (tid << 4);                                    \
      const int r = o >> 7;                                                    \
      const int c = (o & 127) >> 1;                                            \
      gload16(A2 + (size_t)(m0 + r) * 1024 + (k0 + c), (char*)As + o);         \
      gload16(CmT + (size_t)(n0 + r) * 1024 + (k0 + c), (char*)Bs + o);        \
    }                                                                          \
    __syncthreads();                                                           \
    _Pragma("unroll") for (int kk = 0; kk < 64; kk += 32) {                    \
      bf16x8 af[4], bf_[4];                                                    \
      _Pragma("unroll") for (int m4 = 0; m4 < 4; ++m4) af[m4] =                \
          *(const bf16x8*)&As[((wm << 6) + (m4 << 4) + fr) * 64 + kk + ks];    \
      _Pragma("unroll") for (int n4 = 0; n4 < 4; ++n4) bf_[n4] =               \
          *(const bf16x8*)&Bs[((wn << 6) + (n4 << 4) + fr) * 64 + kk + ks];    \
      _Pragma("unroll") for (int m4 = 0; m4 < 4; ++m4)                         \
          _Pragma("unroll") for (int n4 = 0; n4 < 4; ++n4)                     \
              ACC[m4][n4] = __builtin_amdgcn_mfma_f32_16x16x32_bf16(           \
                  af[m4], bf_[n4], ACC[m4][n4], 0, 0, 0);                      \
    }                                                                          \
    __syncthreads();                                                           \
  }

__global__ __launch_bounds__(256) void gemm2_kernel(
    const unsigned short* __restrict__ A2, const unsigned short* __restrict__ CmT,
    const float* __restrict__ x, const float* __restrict__ Df,
    const float* __restrict__ Db, float* __restrict__ out) {
  __shared__ unsigned short As[128 * 64];
  __shared__ unsigned short Bs[128 * 64];
  const int tid = threadIdx.x;
  const int lane = tid & 63;
  const int w = tid >> 6;
  const int wm = w >> 1, wn = w & 1;
  const int fr = lane & 15;
  const int ks = (lane >> 4) << 3;
  const int nt = blockIdx.x & 7, mt = blockIdx.x >> 3;
  const int m0 = mt << 7, n0 = nt << 7;

  f32x4 accf[4][4] = {};
  f32x4 accb[4][4] = {};

  for (int kt = 0; kt < 8; ++kt) GEMM2_KSTEP(accf, kt);
  for (int kt = 8; kt < 16; ++kt) GEMM2_KSTEP(accb, kt);

  const int rb = (lane >> 4) << 2;
#pragma unroll
  for (int n4 = 0; n4 < 4; ++n4) {
    const size_t gn = n0 + (wn << 6) + (n4 << 4) + fr;
    const float dfv = Df[gn], dbv = Db[gn];
#pragma unroll
    for (int m4 = 0; m4 < 4; ++m4) {
#pragma unroll
      for (int r = 0; r < 4; ++r) {
        const size_t gm = m0 + (wm << 6) + (m4 << 4) + rb + r;
        const float xv = x[gm * 1024 + gn];
        const float yf = accf[m4][n4][r] + dfv * xv;
        const float yb = accb[m4][n4][r] + dbv * xv;
        out[gm * 1024 + gn] = gelu_exact(yf) + gelu_exact(yb);
      }
    }
  }
}

// ------------------------------- launch -------------------------------------
extern "C" void kernel_launch(void* const* d_in, const int* in_sizes, int n_in,
                              void* d_out, int out_size, void* d_ws, size_t ws_size,
                              hipStream_t stream) {
  const float* x = (const float*)d_in[0];
  const float* flr = (const float*)d_in[1];
  const float* fim = (const float*)d_in[2];
  const float* fBr = (const float*)d_in[3];
  const float* fBi = (const float*)d_in[4];
  const float* fCr = (const float*)d_in[5];
  const float* fCi = (const float*)d_in[6];
  const float* fD  = (const float*)d_in[7];
  const float* flD = (const float*)d_in[8];
  const float* blr = (const float*)d_in[9];
  const float* bim = (const float*)d_in[10];
  const float* bBr = (const float*)d_in[11];
  const float* bBi = (const float*)d_in[12];
  const float* bCr = (const float*)d_in[13];
  const float* bCi = (const float*)d_in[14];
  const float* bD  = (const float*)d_in[15];
  const float* blD = (const float*)d_in[16];

  char* ws = (char*)d_ws;
  unsigned short* xbf  = (unsigned short*)(ws);                  // 33,554,432
  unsigned short* W    = (unsigned short*)(ws + 33554432);       //  2,097,152
  unsigned short* CmT  = (unsigned short*)(ws + 35651584);       //  2,097,152
  float*          Z    = (float*)(ws + 37748736);                // 67,108,864
  unsigned short* xsbf = (unsigned short*)(ws + 104857600);      // 33,554,432
  float4*         lamp = (float4*)(ws + 138412032);              //      8,192
  float2*         part = (float2*)(ws + 138420224);              //  1,048,576
  float2*         carr = (float2*)(ws + 139468800);              //  1,048,576

  dim3 blk(256);
  cast_x_kernel<<<8192, blk, 0, stream>>>(x, xbf);
  prep_kernel<<<1536, blk, 0, stream>>>(flr, fim, fBr, fBi, fCr, fCi, flD,
                                        blr, bim, bBr, bBi, bCr, bCi, blD,
                                        W, CmT, lamp);
  gemm1_kernel<<<1024, blk, 0, stream>>>(xbf, W, Z);
  scanA_kernel<<<512, blk, 0, stream>>>(Z, lamp, part);
  scanB_kernel<<<8, blk, 0, stream>>>(part, carr, lamp);
  scanC_kernel<<<512, blk, 0, stream>>>(Z, lamp, carr, (unsigned int*)xsbf);
  gemm2_kernel<<<1024, blk, 0, stream>>>(xsbf, CmT, x, fD, bD, (float*)d_out);
}

// Round 2
// 281.198 us; speedup vs baseline: 1.1796x; 1.1796x over previous
//
#include <hip/hip_runtime.h>
#include <math.h>

// ---------------------------------------------------------------------------
// S5 dual (fwd+bwd) SSM:  B=4, L=4096, H=1024, P=256
// Pipeline:
//   cast_x:  x fp32 -> bf16                                  (for GEMM1 A)
//   prep:    build W [1024x1024] bf16 (B_bar rows, re/im interleaved),
//            CmT [1024x1024] bf16 (C^T with -C_imag), lambda params
//   gemm1:   Zb[16384,1024](bf16) = xbf @ W^T
//   scanA:   per-chunk local complex scans, in place on Zb; chunk aggregates
//   scanB:   carry scan across 64 chunks per (b,dir,p) with lambda^64
//   scanC:   xs = local + lambda^i * carry -> bf16 xsbf
//   gemm2:   acc_f/acc_b = xsbf @ CmT^T (K split 512/512);
//            out = gelu(acc_f + Df*x) + gelu(acc_b + Db*x)
// Column layout (inner 1024): c = dir*512 + 2*p + comp  (comp: 0=re, 1=im)
// LDS tiles use st-style XOR swizzle (T2): linear global_load_lds dest,
// pre-swizzled global source column, XOR'd ds_read index (rule #21).
// ---------------------------------------------------------------------------

typedef short bf16x8 __attribute__((ext_vector_type(8)));
typedef float f32x4 __attribute__((ext_vector_type(4)));
typedef unsigned short u16x8 __attribute__((ext_vector_type(8)));

__device__ __forceinline__ unsigned short f2bf(float f) {
  union { float f; unsigned int u; } v; v.f = f;
  unsigned int r = (v.u + 0x7FFFu + ((v.u >> 16) & 1u)) >> 16;
  return (unsigned short)r;
}
__device__ __forceinline__ float bf2f(unsigned short s) {
  union { unsigned int u; float f; } v; v.u = ((unsigned int)s) << 16;
  return v.f;
}
__device__ __forceinline__ float gelu_exact(float v) {
  return 0.5f * v * (1.0f + erff(v * 0.70710678118654752f));
}
__device__ __forceinline__ void gload16(const unsigned short* g, void* l) {
  __builtin_amdgcn_global_load_lds(
      (const __attribute__((address_space(1))) void*)g,
      (__attribute__((address_space(3))) void*)l, 16, 0, 0);
}

// ------------------------------- cast x -> bf16 ----------------------------
__global__ __launch_bounds__(256) void cast_x_kernel(
    const float* __restrict__ x, unsigned short* __restrict__ xbf) {
  const size_t i = (size_t)blockIdx.x * 256 + threadIdx.x;  // 2,097,152 total
  const float4* xv = (const float4*)x;
  float4 a = xv[2 * i], b = xv[2 * i + 1];
  u16x8 r;
  r[0] = f2bf(a.x); r[1] = f2bf(a.y); r[2] = f2bf(a.z); r[3] = f2bf(a.w);
  r[4] = f2bf(b.x); r[5] = f2bf(b.y); r[6] = f2bf(b.z); r[7] = f2bf(b.w);
  *(u16x8*)(xbf + 8 * i) = r;
}

// ------------------------------- prep ---------------------------------------
__global__ __launch_bounds__(256) void prep_kernel(
    const float* __restrict__ flr, const float* __restrict__ fim,
    const float* __restrict__ fBr, const float* __restrict__ fBi,
    const float* __restrict__ fCr, const float* __restrict__ fCi,
    const float* __restrict__ flD,
    const float* __restrict__ blr, const float* __restrict__ bim,
    const float* __restrict__ bBr, const float* __restrict__ bBi,
    const float* __restrict__ bCr, const float* __restrict__ bCi,
    const float* __restrict__ blD,
    unsigned short* __restrict__ W, unsigned short* __restrict__ CmT,
    float4* __restrict__ lamp) {
  const int bid = blockIdx.x, tid = threadIdx.x;
  if (bid < 512) {
    const int dir = bid >> 8, p = bid & 255;
    const float* lr_ = dir ? blr : flr;
    const float* im_ = dir ? bim : fim;
    const float* lD_ = dir ? blD : flD;
    const float* Br_ = dir ? bBr : fBr;
    const float* Bi_ = dir ? bBi : fBi;
    const float Lre = -expf(lr_[p]);
    const float Lim = im_[p];
    const float Dl = expf(lD_[p]);
    const float ar = Lre * Dl, ai = Lim * Dl;
    const float er = expf(ar);
    const float lre = er * cosf(ai), lim = er * sinf(ai);
    const float e64 = expf(64.f * ar);
    const float l64re = e64 * cosf(64.f * ai), l64im = e64 * sinf(64.f * ai);
    float sre = Lre, sim = Lim;
    if (sqrtf(Lre * Lre + Lim * Lim) < 1e-6f) { sre = 1e-6f; sim = 0.f; }
    const float den = sre * sre + sim * sim;
    const float fre = ((lre - 1.f) * sre + lim * sim) / den;
    const float fi2 = (lim * sre - (lre - 1.f) * sim) / den;
    if (tid == 0) lamp[dir * 256 + p] = make_float4(lre, lim, l64re, l64im);
    const size_t rowR = (size_t)(dir * 512 + 2 * p) * 1024;
    const size_t rowI = rowR + 1024;
    for (int h = tid; h < 1024; h += 256) {
      const float Br = Br_[p * 1024 + h], Bi = Bi_[p * 1024 + h];
      W[rowR + h] = f2bf(fre * Br - fi2 * Bi);
      W[rowI + h] = f2bf(fre * Bi + fi2 * Br);
    }
  } else {
    const int h = bid - 512;
    for (int k = tid; k < 1024; k += 256) {
      const int dir = k >> 9, within = k & 511;
      const int p = within >> 1, comp = within & 1;
      const float* C = comp ? (dir ? bCi : fCi) : (dir ? bCr : fCr);
      float v = C[(size_t)h * 256 + p];
      if (comp) v = -v;
      CmT[(size_t)h * 1024 + k] = f2bf(v);
    }
  }
}

// ------------------------------- GEMM1 --------------------------------------
// Zb[m][c] = bf16( sum_h xbf[m][h] * W[c][h] );  M=16384, N=1024, K=1024
__global__ __launch_bounds__(256) void gemm1_kernel(
    const unsigned short* __restrict__ xbf, const unsigned short* __restrict__ W,
    unsigned short* __restrict__ Zb) {
  __shared__ unsigned short As[128 * 64];
  __shared__ unsigned short Bs[128 * 64];
  const int tid = threadIdx.x;
  const int lane = tid & 63;
  const int w = tid >> 6;
  const int wm = w >> 1, wn = w & 1;
  const int fr = lane & 15;
  const int ks = (lane >> 4) << 3;
  const int sw = (fr & 7) << 3;                     // ds_read XOR (elements)
  const int tr = tid >> 3;                          // staging row-within-32
  const int csw = ((tid & 7) ^ (tr & 7)) << 3;      // staging src col (elems)
  const int bsw = ((blockIdx.x & 7) << 7) + (blockIdx.x >> 3);  // XCD swizzle
  const int nt = bsw & 7, mt = bsw >> 3;
  const int m0 = mt << 7, n0 = nt << 7;

  f32x4 acc[4][4] = {};

  for (int kt = 0; kt < 16; ++kt) {
    const int k0 = kt << 6;
#pragma unroll
    for (int i = 0; i < 4; ++i) {
      const int r = (i << 5) + tr;
      const int o = (i << 12) + (tid << 4);
      gload16(xbf + (size_t)(m0 + r) * 1024 + (k0 + csw), (char*)As + o);
      gload16(W + (size_t)(n0 + r) * 1024 + (k0 + csw), (char*)Bs + o);
    }
    __syncthreads();
#pragma unroll
    for (int kk = 0; kk < 64; kk += 32) {
      bf16x8 af[4], bf_[4];
#pragma unroll
      for (int m4 = 0; m4 < 4; ++m4) {
        const int row = (wm << 6) + (m4 << 4) + fr;
        af[m4] = *(const bf16x8*)&As[row * 64 + ((kk + ks) ^ sw)];
      }
#pragma unroll
      for (int n4 = 0; n4 < 4; ++n4) {
        const int row = (wn << 6) + (n4 << 4) + fr;
        bf_[n4] = *(const bf16x8*)&Bs[row * 64 + ((kk + ks) ^ sw)];
      }
#pragma unroll
      for (int m4 = 0; m4 < 4; ++m4)
#pragma unroll
        for (int n4 = 0; n4 < 4; ++n4)
          acc[m4][n4] = __builtin_amdgcn_mfma_f32_16x16x32_bf16(
              af[m4], bf_[n4], acc[m4][n4], 0, 0, 0);
    }
    __syncthreads();
  }
  const int rb = (lane >> 4) << 2;
#pragma unroll
  for (int m4 = 0; m4 < 4; ++m4)
#pragma unroll
    for (int n4 = 0; n4 < 4; ++n4) {
      const size_t gn = n0 + (wn << 6) + (n4 << 4) + fr;
#pragma unroll
      for (int r = 0; r < 4; ++r) {
        const size_t gm = m0 + (wm << 6) + (m4 << 4) + rb + r;
        Zb[gm * 1024 + gn] = f2bf(acc[m4][n4][r]);
      }
    }
}

// ------------------------------- scans --------------------------------------
// Zb viewed as u32 pairs: Zp[m][512], col = dir*256 + p, packed (re, im) bf16.
__global__ __launch_bounds__(256) void scanA_kernel(
    unsigned int* __restrict__ Zp, const float4* __restrict__ lamp,
    float2* __restrict__ partials) {
  const int p = threadIdx.x;
  const int chunk = blockIdx.x & 63;
  const int dir = (blockIdx.x >> 6) & 1;
  const int b = blockIdx.x >> 7;
  const float4 lp = lamp[dir * 256 + p];
  const float lre = lp.x, lim = lp.y;
  const size_t col = (size_t)dir * 256 + p;
  const size_t mbase = (size_t)b * 4096 + (size_t)chunk * 64;
  float sre = 0.f, sim = 0.f;
  if (dir == 0) {
    for (int i = 0; i < 64; ++i) {
      const size_t idx = (mbase + i) * 512 + col;
      const unsigned int u = Zp[idx];
      const float ur = bf2f((unsigned short)u), ui = bf2f((unsigned short)(u >> 16));
      const float nr = fmaf(lre, sre, fmaf(-lim, sim, ur));
      const float ni = fmaf(lre, sim, fmaf(lim, sre, ui));
      sre = nr; sim = ni;
      Zp[idx] = (unsigned int)f2bf(sre) | ((unsigned int)f2bf(sim) << 16);
    }
  } else {
    for (int i = 63; i >= 0; --i) {
      const size_t idx = (mbase + i) * 512 + col;
      const unsigned int u = Zp[idx];
      const float ur = bf2f((unsigned short)u), ui = bf2f((unsigned short)(u >> 16));
      const float nr = fmaf(lre, sre, fmaf(-lim, sim, ur));
      const float ni = fmaf(lre, sim, fmaf(lim, sre, ui));
      sre = nr; sim = ni;
      Zp[idx] = (unsigned int)f2bf(sre) | ((unsigned int)f2bf(sim) << 16);
    }
  }
  partials[((size_t)(b * 2 + dir) * 256 + p) * 64 + chunk] = make_float2(sre, sim);
}

__global__ __launch_bounds__(256) void scanB_kernel(
    const float2* __restrict__ partials, float2* __restrict__ carries,
    const float4* __restrict__ lamp) {
  const int t = blockIdx.x * 256 + threadIdx.x;  // < 2048
  const int p = t & 255;
  const int dir = (t >> 8) & 1;
  const int b = t >> 9;
  const float4 lp = lamp[dir * 256 + p];
  const float ar = lp.z, ai = lp.w;  // lambda^64
  const size_t base = ((size_t)(b * 2 + dir) * 256 + p) * 64;
  float cr = 0.f, ci = 0.f;
  if (dir == 0) {
    for (int c = 0; c < 64; ++c) {
      carries[base + c] = make_float2(cr, ci);
      float2 s = partials[base + c];
      float nr = fmaf(ar, cr, fmaf(-ai, ci, s.x));
      float ni = fmaf(ar, ci, fmaf(ai, cr, s.y));
      cr = nr; ci = ni;
    }
  } else {
    for (int c = 63; c >= 0; --c) {
      carries[base + c] = make_float2(cr, ci);
      float2 s = partials[base + c];
      float nr = fmaf(ar, cr, fmaf(-ai, ci, s.x));
      float ni = fmaf(ar, ci, fmaf(ai, cr, s.y));
      cr = nr; ci = ni;
    }
  }
}

__global__ __launch_bounds__(256) void scanC_kernel(
    const unsigned int* __restrict__ Zp, const float4* __restrict__ lamp,
    const float2* __restrict__ carries, unsigned int* __restrict__ xsbf) {
  const int p = threadIdx.x;
  const int chunk = blockIdx.x & 63;
  const int dir = (blockIdx.x >> 6) & 1;
  const int b = blockIdx.x >> 7;
  const float4 lp = lamp[dir * 256 + p];
  const float lre = lp.x, lim = lp.y;
  const size_t col = (size_t)dir * 256 + p;
  const size_t mbase = (size_t)b * 4096 + (size_t)chunk * 64;
  const float2 K = carries[((size_t)(b * 2 + dir) * 256 + p) * 64 + chunk];
  float qr = lre * K.x - lim * K.y;
  float qi = lre * K.y + lim * K.x;
  if (dir == 0) {
    for (int i = 0; i < 64; ++i) {
      const size_t idx = (mbase + i) * 512 + col;
      const unsigned int u = Zp[idx];
      const float vr = bf2f((unsigned short)u) + qr;
      const float vi = bf2f((unsigned short)(u >> 16)) + qi;
      xsbf[idx] = (unsigned int)f2bf(vr) | ((unsigned int)f2bf(vi) << 16);
      const float t2 = lre * qr - lim * qi;
      qi = lre * qi + lim * qr; qr = t2;
    }
  } else {
    for (int i = 63; i >= 0; --i) {
      const size_t idx = (mbase + i) * 512 + col;
      const unsigned int u = Zp[idx];
      const float vr = bf2f((unsigned short)u) + qr;
      const float vi = bf2f((unsigned short)(u >> 16)) + qi;
      xsbf[idx] = (unsigned int)f2bf(vr) | ((unsigned int)f2bf(vi) << 16);
      const float t2 = lre * qr - lim * qi;
      qi = lre * qi + lim * qr; qr = t2;
    }
  }
}

// ------------------------------- GEMM2 + epilogue ---------------------------
// acc_f[m][h] = sum_{k<512} A2[m][k]*CmT[h][k]; acc_b over k in [512,1024)
// out = gelu(acc_f + Df*x) + gelu(acc_b + Db*x)
#define GEMM2_KSTEP(ACC, KT)                                                   \
  {                                                                            \
    const int k0 = (KT) << 6;                                                  \
    _Pragma("unroll") for (int i = 0; i < 4; ++i) {                            \
      const int r = (i << 5) + tr;                                             \
      const int o = (i << 12) + (tid << 4);                                    \
      gload16(A2 + (size_t)(m0 + r) * 1024 + (k0 + csw), (char*)As + o);       \
      gload16(CmT + (size_t)(n0 + r) * 1024 + (k0 + csw), (char*)Bs + o);      \
    }                                                                          \
    __syncthreads();                                                           \
    _Pragma("unroll") for (int kk = 0; kk < 64; kk += 32) {                    \
      bf16x8 af[4], bf_[4];                                                    \
      _Pragma("unroll") for (int m4 = 0; m4 < 4; ++m4) {                       \
        const int row = (wm << 6) + (m4 << 4) + fr;                            \
        af[m4] = *(const bf16x8*)&As[row * 64 + ((kk + ks) ^ sw)];             \
      }                                                                        \
      _Pragma("unroll") for (int n4 = 0; n4 < 4; ++n4) {                       \
        const int row = (wn << 6) + (n4 << 4) + fr;                            \
        bf_[n4] = *(const bf16x8*)&Bs[row * 64 + ((kk + ks) ^ sw)];            \
      }                                                                        \
      _Pragma("unroll") for (int m4 = 0; m4 < 4; ++m4)                         \
          _Pragma("unroll") for (int n4 = 0; n4 < 4; ++n4)                     \
              ACC[m4][n4] = __builtin_amdgcn_mfma_f32_16x16x32_bf16(           \
                  af[m4], bf_[n4], ACC[m4][n4], 0, 0, 0);                      \
    }                                                                          \
    __syncthreads();                                                           \
  }

__global__ __launch_bounds__(256) void gemm2_kernel(
    const unsigned short* __restrict__ A2, const unsigned short* __restrict__ CmT,
    const float* __restrict__ x, const float* __restrict__ Df,
    const float* __restrict__ Db, float* __restrict__ out) {
  __shared__ unsigned short As[128 * 64];
  __shared__ unsigned short Bs[128 * 64];
  const int tid = threadIdx.x;
  const int lane = tid & 63;
  const int w = tid >> 6;
  const int wm = w >> 1, wn = w & 1;
  const int fr = lane & 15;
  const int ks = (lane >> 4) << 3;
  const int sw = (fr & 7) << 3;
  const int tr = tid >> 3;
  const int csw = ((tid & 7) ^ (tr & 7)) << 3;
  const int bsw = ((blockIdx.x & 7) << 7) + (blockIdx.x >> 3);  // XCD swizzle
  const int nt = bsw & 7, mt = bsw >> 3;
  const int m0 = mt << 7, n0 = nt << 7;

  f32x4 accf[4][4] = {};
  f32x4 accb[4][4] = {};

  for (int kt = 0; kt < 8; ++kt) GEMM2_KSTEP(accf, kt);
  for (int kt = 8; kt < 16; ++kt) GEMM2_KSTEP(accb, kt);

  const int rb = (lane >> 4) << 2;
#pragma unroll
  for (int n4 = 0; n4 < 4; ++n4) {
    const size_t gn = n0 + (wn << 6) + (n4 << 4) + fr;
    const float dfv = Df[gn], dbv = Db[gn];
#pragma unroll
    for (int m4 = 0; m4 < 4; ++m4) {
#pragma unroll
      for (int r = 0; r < 4; ++r) {
        const size_t gm = m0 + (wm << 6) + (m4 << 4) + rb + r;
        const float xv = x[gm * 1024 + gn];
        const float yf = accf[m4][n4][r] + dfv * xv;
        const float yb = accb[m4][n4][r] + dbv * xv;
        out[gm * 1024 + gn] = gelu_exact(yf) + gelu_exact(yb);
      }
    }
  }
}

// ------------------------------- launch -------------------------------------
extern "C" void kernel_launch(void* const* d_in, const int* in_sizes, int n_in,
                              void* d_out, int out_size, void* d_ws, size_t ws_size,
                              hipStream_t stream) {
  const float* x = (const float*)d_in[0];
  const float* flr = (const float*)d_in[1];
  const float* fim = (const float*)d_in[2];
  const float* fBr = (const float*)d_in[3];
  const float* fBi = (const float*)d_in[4];
  const float* fCr = (const float*)d_in[5];
  const float* fCi = (const float*)d_in[6];
  const float* fD  = (const float*)d_in[7];
  const float* flD = (const float*)d_in[8];
  const float* blr = (const float*)d_in[9];
  const float* bim = (const float*)d_in[10];
  const float* bBr = (const float*)d_in[11];
  const float* bBi = (const float*)d_in[12];
  const float* bCr = (const float*)d_in[13];
  const float* bCi = (const float*)d_in[14];
  const float* bD  = (const float*)d_in[15];
  const float* blD = (const float*)d_in[16];

  char* ws = (char*)d_ws;
  unsigned short* xbf  = (unsigned short*)(ws);                  // 33,554,432
  unsigned short* W    = (unsigned short*)(ws + 33554432);       //  2,097,152
  unsigned short* CmT  = (unsigned short*)(ws + 35651584);       //  2,097,152
  unsigned short* Zb   = (unsigned short*)(ws + 37748736);       // 33,554,432
  unsigned short* xsbf = (unsigned short*)(ws + 71303168);       // 33,554,432
  float4*         lamp = (float4*)(ws + 104857600);              //      8,192
  float2*         part = (float2*)(ws + 104865792);              //  1,048,576
  float2*         carr = (float2*)(ws + 105914368);              //  1,048,576

  dim3 blk(256);
  cast_x_kernel<<<8192, blk, 0, stream>>>(x, xbf);
  prep_kernel<<<1536, blk, 0, stream>>>(flr, fim, fBr, fBi, fCr, fCi, flD,
                                        blr, bim, bBr, bBi, bCr, bCi, blD,
                                        W, CmT, lamp);
  gemm1_kernel<<<1024, blk, 0, stream>>>(xbf, W, Zb);
  scanA_kernel<<<512, blk, 0, stream>>>((unsigned int*)Zb, lamp, part);
  scanB_kernel<<<8, blk, 0, stream>>>(part, carr, lamp);
  scanC_kernel<<<512, blk, 0, stream>>>((unsigned int*)Zb, lamp, carr,
                                        (unsigned int*)xsbf);
  gemm2_kernel<<<1024, blk, 0, stream>>>(xsbf, CmT, x, fD, bD, (float*)d_out);
}

// Round 3
// 215.642 us; speedup vs baseline: 1.5382x; 1.3040x over previous
//
#include <hip/hip_runtime.h>
#include <math.h>

// ---------------------------------------------------------------------------
// S5 dual (fwd+bwd) SSM:  B=4, L=4096, H=1024, P=256
// Pipeline:
//   cast_x:  x fp32 -> bf16                                  (for GEMM1 A)
//   prep:    build W [1024x1024] bf16 (B_bar rows, re/im interleaved),
//            CmT [1024x1024] bf16 (C^T with -C_imag), lambda params
//   gemm1:   Zb[16384,1024](bf16) = xbf @ W^T      (128x128 tile, 4x4/wave)
//   scanA:   per-chunk local complex scans, in place on Zb; chunk aggregates
//   scanB:   carry scan across 64 chunks per (b,dir,p) with lambda^64
//   scanC:   xs = local + lambda^i * carry -> bf16 xsbf
//   gemm2:   BM=128 BN=64 tile (dual accumulators fwd/bwd, K split 512/512);
//            out = gelu(acc_f + Df*x) + gelu(acc_b + Db*x)
//            NOTE: dual acc at 128x128 tile = 268 regs/lane -> 1 wave/SIMD
//            occupancy cliff (R2 counters); 128x64 halves acc to 64 regs.
// Column layout (inner 1024): c = dir*512 + 2*p + comp  (comp: 0=re, 1=im)
// LDS tiles use XOR swizzle (T2): linear global_load_lds dest, pre-swizzled
// global source column, XOR'd ds_read index (rule #21). R2: conflicts == 0.
// ---------------------------------------------------------------------------

typedef short bf16x8 __attribute__((ext_vector_type(8)));
typedef float f32x4 __attribute__((ext_vector_type(4)));
typedef unsigned short u16x8 __attribute__((ext_vector_type(8)));

__device__ __forceinline__ unsigned short f2bf(float f) {
  union { float f; unsigned int u; } v; v.f = f;
  unsigned int r = (v.u + 0x7FFFu + ((v.u >> 16) & 1u)) >> 16;
  return (unsigned short)r;
}
__device__ __forceinline__ float bf2f(unsigned short s) {
  union { unsigned int u; float f; } v; v.u = ((unsigned int)s) << 16;
  return v.f;
}
__device__ __forceinline__ float gelu_exact(float v) {
  return 0.5f * v * (1.0f + erff(v * 0.70710678118654752f));
}
__device__ __forceinline__ void gload16(const unsigned short* g, void* l) {
  __builtin_amdgcn_global_load_lds(
      (const __attribute__((address_space(1))) void*)g,
      (__attribute__((address_space(3))) void*)l, 16, 0, 0);
}

// ------------------------------- cast x -> bf16 ----------------------------
__global__ __launch_bounds__(256) void cast_x_kernel(
    const float* __restrict__ x, unsigned short* __restrict__ xbf) {
  const size_t i = (size_t)blockIdx.x * 256 + threadIdx.x;  // 2,097,152 total
  const float4* xv = (const float4*)x;
  float4 a = xv[2 * i], b = xv[2 * i + 1];
  u16x8 r;
  r[0] = f2bf(a.x); r[1] = f2bf(a.y); r[2] = f2bf(a.z); r[3] = f2bf(a.w);
  r[4] = f2bf(b.x); r[5] = f2bf(b.y); r[6] = f2bf(b.z); r[7] = f2bf(b.w);
  *(u16x8*)(xbf + 8 * i) = r;
}

// ------------------------------- prep ---------------------------------------
__global__ __launch_bounds__(256) void prep_kernel(
    const float* __restrict__ flr, const float* __restrict__ fim,
    const float* __restrict__ fBr, const float* __restrict__ fBi,
    const float* __restrict__ fCr, const float* __restrict__ fCi,
    const float* __restrict__ flD,
    const float* __restrict__ blr, const float* __restrict__ bim,
    const float* __restrict__ bBr, const float* __restrict__ bBi,
    const float* __restrict__ bCr, const float* __restrict__ bCi,
    const float* __restrict__ blD,
    unsigned short* __restrict__ W, unsigned short* __restrict__ CmT,
    float4* __restrict__ lamp) {
  const int bid = blockIdx.x, tid = threadIdx.x;
  if (bid < 512) {
    const int dir = bid >> 8, p = bid & 255;
    const float* lr_ = dir ? blr : flr;
    const float* im_ = dir ? bim : fim;
    const float* lD_ = dir ? blD : flD;
    const float* Br_ = dir ? bBr : fBr;
    const float* Bi_ = dir ? bBi : fBi;
    const float Lre = -expf(lr_[p]);
    const float Lim = im_[p];
    const float Dl = expf(lD_[p]);
    const float ar = Lre * Dl, ai = Lim * Dl;
    const float er = expf(ar);
    const float lre = er * cosf(ai), lim = er * sinf(ai);
    const float e64 = expf(64.f * ar);
    const float l64re = e64 * cosf(64.f * ai), l64im = e64 * sinf(64.f * ai);
    float sre = Lre, sim = Lim;
    if (sqrtf(Lre * Lre + Lim * Lim) < 1e-6f) { sre = 1e-6f; sim = 0.f; }
    const float den = sre * sre + sim * sim;
    const float fre = ((lre - 1.f) * sre + lim * sim) / den;
    const float fi2 = (lim * sre - (lre - 1.f) * sim) / den;
    if (tid == 0) lamp[dir * 256 + p] = make_float4(lre, lim, l64re, l64im);
    const size_t rowR = (size_t)(dir * 512 + 2 * p) * 1024;
    const size_t rowI = rowR + 1024;
    for (int h = tid; h < 1024; h += 256) {
      const float Br = Br_[p * 1024 + h], Bi = Bi_[p * 1024 + h];
      W[rowR + h] = f2bf(fre * Br - fi2 * Bi);
      W[rowI + h] = f2bf(fre * Bi + fi2 * Br);
    }
  } else {
    const int h = bid - 512;
    for (int k = tid; k < 1024; k += 256) {
      const int dir = k >> 9, within = k & 511;
      const int p = within >> 1, comp = within & 1;
      const float* C = comp ? (dir ? bCi : fCi) : (dir ? bCr : fCr);
      float v = C[(size_t)h * 256 + p];
      if (comp) v = -v;
      CmT[(size_t)h * 1024 + k] = f2bf(v);
    }
  }
}

// ------------------------------- GEMM1 --------------------------------------
// Zb[m][c] = bf16( sum_h xbf[m][h] * W[c][h] );  M=16384, N=1024, K=1024
__global__ __launch_bounds__(256) void gemm1_kernel(
    const unsigned short* __restrict__ xbf, const unsigned short* __restrict__ W,
    unsigned short* __restrict__ Zb) {
  __shared__ unsigned short As[128 * 64];
  __shared__ unsigned short Bs[128 * 64];
  const int tid = threadIdx.x;
  const int lane = tid & 63;
  const int w = tid >> 6;
  const int wm = w >> 1, wn = w & 1;
  const int fr = lane & 15;
  const int ks = (lane >> 4) << 3;
  const int sw = (fr & 7) << 3;                     // ds_read XOR (elements)
  const int tr = tid >> 3;                          // staging row-within-32
  const int csw = ((tid & 7) ^ (tr & 7)) << 3;      // staging src col (elems)
  const int bsw = ((blockIdx.x & 7) << 7) + (blockIdx.x >> 3);  // XCD swizzle
  const int nt = bsw & 7, mt = bsw >> 3;
  const int m0 = mt << 7, n0 = nt << 7;

  f32x4 acc[4][4] = {};

  for (int kt = 0; kt < 16; ++kt) {
    const int k0 = kt << 6;
#pragma unroll
    for (int i = 0; i < 4; ++i) {
      const int r = (i << 5) + tr;
      const int o = (i << 12) + (tid << 4);
      gload16(xbf + (size_t)(m0 + r) * 1024 + (k0 + csw), (char*)As + o);
      gload16(W + (size_t)(n0 + r) * 1024 + (k0 + csw), (char*)Bs + o);
    }
    __syncthreads();
#pragma unroll
    for (int kk = 0; kk < 64; kk += 32) {
      bf16x8 af[4], bf_[4];
#pragma unroll
      for (int m4 = 0; m4 < 4; ++m4) {
        const int row = (wm << 6) + (m4 << 4) + fr;
        af[m4] = *(const bf16x8*)&As[row * 64 + ((kk + ks) ^ sw)];
      }
#pragma unroll
      for (int n4 = 0; n4 < 4; ++n4) {
        const int row = (wn << 6) + (n4 << 4) + fr;
        bf_[n4] = *(const bf16x8*)&Bs[row * 64 + ((kk + ks) ^ sw)];
      }
#pragma unroll
      for (int m4 = 0; m4 < 4; ++m4)
#pragma unroll
        for (int n4 = 0; n4 < 4; ++n4)
          acc[m4][n4] = __builtin_amdgcn_mfma_f32_16x16x32_bf16(
              af[m4], bf_[n4], acc[m4][n4], 0, 0, 0);
    }
    __syncthreads();
  }
  const int rb = (lane >> 4) << 2;
#pragma unroll
  for (int m4 = 0; m4 < 4; ++m4)
#pragma unroll
    for (int n4 = 0; n4 < 4; ++n4) {
      const size_t gn = n0 + (wn << 6) + (n4 << 4) + fr;
#pragma unroll
      for (int r = 0; r < 4; ++r) {
        const size_t gm = m0 + (wm << 6) + (m4 << 4) + rb + r;
        Zb[gm * 1024 + gn] = f2bf(acc[m4][n4][r]);
      }
    }
}

// ------------------------------- scans --------------------------------------
// Zb viewed as u32 pairs: Zp[m][512], col = dir*256 + p, packed (re, im) bf16.
__global__ __launch_bounds__(256) void scanA_kernel(
    unsigned int* __restrict__ Zp, const float4* __restrict__ lamp,
    float2* __restrict__ partials) {
  const int p = threadIdx.x;
  const int chunk = blockIdx.x & 63;
  const int dir = (blockIdx.x >> 6) & 1;
  const int b = blockIdx.x >> 7;
  const float4 lp = lamp[dir * 256 + p];
  const float lre = lp.x, lim = lp.y;
  const size_t col = (size_t)dir * 256 + p;
  const size_t mbase = (size_t)b * 4096 + (size_t)chunk * 64;
  float sre = 0.f, sim = 0.f;
  if (dir == 0) {
    for (int i = 0; i < 64; ++i) {
      const size_t idx = (mbase + i) * 512 + col;
      const unsigned int u = Zp[idx];
      const float ur = bf2f((unsigned short)u), ui = bf2f((unsigned short)(u >> 16));
      const float nr = fmaf(lre, sre, fmaf(-lim, sim, ur));
      const float ni = fmaf(lre, sim, fmaf(lim, sre, ui));
      sre = nr; sim = ni;
      Zp[idx] = (unsigned int)f2bf(sre) | ((unsigned int)f2bf(sim) << 16);
    }
  } else {
    for (int i = 63; i >= 0; --i) {
      const size_t idx = (mbase + i) * 512 + col;
      const unsigned int u = Zp[idx];
      const float ur = bf2f((unsigned short)u), ui = bf2f((unsigned short)(u >> 16));
      const float nr = fmaf(lre, sre, fmaf(-lim, sim, ur));
      const float ni = fmaf(lre, sim, fmaf(lim, sre, ui));
      sre = nr; sim = ni;
      Zp[idx] = (unsigned int)f2bf(sre) | ((unsigned int)f2bf(sim) << 16);
    }
  }
  partials[((size_t)(b * 2 + dir) * 256 + p) * 64 + chunk] = make_float2(sre, sim);
}

__global__ __launch_bounds__(256) void scanB_kernel(
    const float2* __restrict__ partials, float2* __restrict__ carries,
    const float4* __restrict__ lamp) {
  const int t = blockIdx.x * 256 + threadIdx.x;  // < 2048
  const int p = t & 255;
  const int dir = (t >> 8) & 1;
  const int b = t >> 9;
  const float4 lp = lamp[dir * 256 + p];
  const float ar = lp.z, ai = lp.w;  // lambda^64
  const size_t base = ((size_t)(b * 2 + dir) * 256 + p) * 64;
  float cr = 0.f, ci = 0.f;
  if (dir == 0) {
    for (int c = 0; c < 64; ++c) {
      carries[base + c] = make_float2(cr, ci);
      float2 s = partials[base + c];
      float nr = fmaf(ar, cr, fmaf(-ai, ci, s.x));
      float ni = fmaf(ar, ci, fmaf(ai, cr, s.y));
      cr = nr; ci = ni;
    }
  } else {
    for (int c = 63; c >= 0; --c) {
      carries[base + c] = make_float2(cr, ci);
      float2 s = partials[base + c];
      float nr = fmaf(ar, cr, fmaf(-ai, ci, s.x));
      float ni = fmaf(ar, ci, fmaf(ai, cr, s.y));
      cr = nr; ci = ni;
    }
  }
}

__global__ __launch_bounds__(256) void scanC_kernel(
    const unsigned int* __restrict__ Zp, const float4* __restrict__ lamp,
    const float2* __restrict__ carries, unsigned int* __restrict__ xsbf) {
  const int p = threadIdx.x;
  const int chunk = blockIdx.x & 63;
  const int dir = (blockIdx.x >> 6) & 1;
  const int b = blockIdx.x >> 7;
  const float4 lp = lamp[dir * 256 + p];
  const float lre = lp.x, lim = lp.y;
  const size_t col = (size_t)dir * 256 + p;
  const size_t mbase = (size_t)b * 4096 + (size_t)chunk * 64;
  const float2 K = carries[((size_t)(b * 2 + dir) * 256 + p) * 64 + chunk];
  float qr = lre * K.x - lim * K.y;
  float qi = lre * K.y + lim * K.x;
  if (dir == 0) {
    for (int i = 0; i < 64; ++i) {
      const size_t idx = (mbase + i) * 512 + col;
      const unsigned int u = Zp[idx];
      const float vr = bf2f((unsigned short)u) + qr;
      const float vi = bf2f((unsigned short)(u >> 16)) + qi;
      xsbf[idx] = (unsigned int)f2bf(vr) | ((unsigned int)f2bf(vi) << 16);
      const float t2 = lre * qr - lim * qi;
      qi = lre * qi + lim * qr; qr = t2;
    }
  } else {
    for (int i = 63; i >= 0; --i) {
      const size_t idx = (mbase + i) * 512 + col;
      const unsigned int u = Zp[idx];
      const float vr = bf2f((unsigned short)u) + qr;
      const float vi = bf2f((unsigned short)(u >> 16)) + qi;
      xsbf[idx] = (unsigned int)f2bf(vr) | ((unsigned int)f2bf(vi) << 16);
      const float t2 = lre * qr - lim * qi;
      qi = lre * qi + lim * qr; qr = t2;
    }
  }
}

// ------------------------------- GEMM2 + epilogue ---------------------------
// BM=128, BN=64, 256 threads (2x2 waves), per-wave 64x32, dual acc 4x2 each.
// acc_f[m][h] = sum_{k<512} A2[m][k]*CmT[h][k]; acc_b over k in [512,1024)
// out = gelu(acc_f + Df*x) + gelu(acc_b + Db*x)
#define GEMM2_KSTEP(ACC, KT)                                                   \
  {                                                                            \
    const int k0 = (KT) << 6;                                                  \
    _Pragma("unroll") for (int i = 0; i < 4; ++i) {                            \
      const int r = (i << 5) + tr;                                             \
      const int o = (i << 12) + (tid << 4);                                    \
      gload16(A2 + (size_t)(m0 + r) * 1024 + (k0 + csw), (char*)As + o);       \
    }                                                                          \
    _Pragma("unroll") for (int i = 0; i < 2; ++i) {                            \
      const int r = (i << 5) + tr;                                             \
      const int o = (i << 12) + (tid << 4);                                    \
      gload16(CmT + (size_t)(n0 + r) * 1024 + (k0 + csw), (char*)Bs + o);      \
    }                                                                          \
    __syncthreads();                                                           \
    _Pragma("unroll") for (int kk = 0; kk < 64; kk += 32) {                    \
      bf16x8 af[4], bf_[2];                                                    \
      _Pragma("unroll") for (int m4 = 0; m4 < 4; ++m4) {                       \
        const int row = (wm << 6) + (m4 << 4) + fr;                            \
        af[m4] = *(const bf16x8*)&As[row * 64 + ((kk + ks) ^ sw)];             \
      }                                                                        \
      _Pragma("unroll") for (int n2 = 0; n2 < 2; ++n2) {                       \
        const int row = (wn << 5) + (n2 << 4) + fr;                            \
        bf_[n2] = *(const bf16x8*)&Bs[row * 64 + ((kk + ks) ^ sw)];            \
      }                                                                        \
      _Pragma("unroll") for (int m4 = 0; m4 < 4; ++m4)                         \
          _Pragma("unroll") for (int n2 = 0; n2 < 2; ++n2)                     \
              ACC[m4][n2] = __builtin_amdgcn_mfma_f32_16x16x32_bf16(           \
                  af[m4], bf_[n2], ACC[m4][n2], 0, 0, 0);                      \
    }                                                                          \
    __syncthreads();                                                           \
  }

__global__ __launch_bounds__(256) void gemm2_kernel(
    const unsigned short* __restrict__ A2, const unsigned short* __restrict__ CmT,
    const unsigned short* __restrict__ xbf, const float* __restrict__ Df,
    const float* __restrict__ Db, float* __restrict__ out) {
  __shared__ unsigned short As[128 * 64];
  __shared__ unsigned short Bs[64 * 64];
  const int tid = threadIdx.x;
  const int lane = tid & 63;
  const int w = tid >> 6;
  const int wm = w >> 1, wn = w & 1;
  const int fr = lane & 15;
  const int ks = (lane >> 4) << 3;
  const int sw = (fr & 7) << 3;
  const int tr = tid >> 3;
  const int csw = ((tid & 7) ^ (tr & 7)) << 3;
  const int bsw = ((blockIdx.x & 7) << 8) + (blockIdx.x >> 3);  // XCD swizzle
  const int nt = bsw & 15, mt = bsw >> 4;                        // 16 N-tiles
  const int m0 = mt << 7, n0 = nt << 6;

  f32x4 accf[4][2] = {};
  f32x4 accb[4][2] = {};

  for (int kt = 0; kt < 8; ++kt) GEMM2_KSTEP(accf, kt);
  for (int kt = 8; kt < 16; ++kt) GEMM2_KSTEP(accb, kt);

  const int rb = (lane >> 4) << 2;
#pragma unroll
  for (int n2 = 0; n2 < 2; ++n2) {
    const size_t gn = n0 + (wn << 5) + (n2 << 4) + fr;
    const float dfv = Df[gn], dbv = Db[gn];
#pragma unroll
    for (int m4 = 0; m4 < 4; ++m4) {
#pragma unroll
      for (int r = 0; r < 4; ++r) {
        const size_t gm = m0 + (wm << 6) + (m4 << 4) + rb + r;
        const float xv = bf2f(xbf[gm * 1024 + gn]);
        const float yf = accf[m4][n2][r] + dfv * xv;
        const float yb = accb[m4][n2][r] + dbv * xv;
        out[gm * 1024 + gn] = gelu_exact(yf) + gelu_exact(yb);
      }
    }
  }
}

// ------------------------------- launch -------------------------------------
extern "C" void kernel_launch(void* const* d_in, const int* in_sizes, int n_in,
                              void* d_out, int out_size, void* d_ws, size_t ws_size,
                              hipStream_t stream) {
  const float* x = (const float*)d_in[0];
  const float* flr = (const float*)d_in[1];
  const float* fim = (const float*)d_in[2];
  const float* fBr = (const float*)d_in[3];
  const float* fBi = (const float*)d_in[4];
  const float* fCr = (const float*)d_in[5];
  const float* fCi = (const float*)d_in[6];
  const float* fD  = (const float*)d_in[7];
  const float* flD = (const float*)d_in[8];
  const float* blr = (const float*)d_in[9];
  const float* bim = (const float*)d_in[10];
  const float* bBr = (const float*)d_in[11];
  const float* bBi = (const float*)d_in[12];
  const float* bCr = (const float*)d_in[13];
  const float* bCi = (const float*)d_in[14];
  const float* bD  = (const float*)d_in[15];
  const float* blD = (const float*)d_in[16];

  char* ws = (char*)d_ws;
  unsigned short* xbf  = (unsigned short*)(ws);                  // 33,554,432
  unsigned short* W    = (unsigned short*)(ws + 33554432);       //  2,097,152
  unsigned short* CmT  = (unsigned short*)(ws + 35651584);       //  2,097,152
  unsigned short* Zb   = (unsigned short*)(ws + 37748736);       // 33,554,432
  unsigned short* xsbf = (unsigned short*)(ws + 71303168);       // 33,554,432
  float4*         lamp = (float4*)(ws + 104857600);              //      8,192
  float2*         part = (float2*)(ws + 104865792);              //  1,048,576
  float2*         carr = (float2*)(ws + 105914368);              //  1,048,576

  dim3 blk(256);
  cast_x_kernel<<<8192, blk, 0, stream>>>(x, xbf);
  prep_kernel<<<1536, blk, 0, stream>>>(flr, fim, fBr, fBi, fCr, fCi, flD,
                                        blr, bim, bBr, bBi, bCr, bCi, blD,
                                        W, CmT, lamp);
  gemm1_kernel<<<1024, blk, 0, stream>>>(xbf, W, Zb);
  scanA_kernel<<<512, blk, 0, stream>>>((unsigned int*)Zb, lamp, part);
  scanB_kernel<<<8, blk, 0, stream>>>(part, carr, lamp);
  scanC_kernel<<<512, blk, 0, stream>>>((unsigned int*)Zb, lamp, carr,
                                        (unsigned int*)xsbf);
  gemm2_kernel<<<2048, blk, 0, stream>>>(xsbf, CmT, xbf, fD, bD, (float*)d_out);
}

// Round 4
// 162.887 us; speedup vs baseline: 2.0363x; 1.3239x over previous
//
#include <hip/hip_runtime.h>
#include <math.h>

// ---------------------------------------------------------------------------
// S5 dual (fwd+bwd) SSM:  B=4, L=4096, H=1024, P=256
// Pipeline:
//   cast_x:  x fp32 -> bf16                                  (for GEMM1 A)
//   prep:    build W [1024x1024] bf16 (B_bar rows, re/im interleaved),
//            CmT [1024x1024] bf16 (C^T with -C_imag), lambda params
//   gemm1:   Zb[16384,1024](bf16) = xbf @ W^T      (128x128 tile, 4x4/wave)
//   scanA:   per-chunk local complex scans, in place on Zb; chunk aggregates
//   scanB:   carry scan across 64 chunks per (b,dir,p) with lambda^64
//   scanC:   xs = local + lambda^i * carry -> bf16 xsbf
//   gemm2:   128x128 tile, per-wave 64x64, DUAL acc (fwd kt 0..7 / bwd 8..15)
//            out = gelu(acc_f + Df*x) + gelu(acc_b + Db*x)   (tanh-form gelu)
//            R3 lesson: BN=64 halved FLOP-per-ds_read -> LDS-bound at 11%
//            MfmaUtil; 128x128 dual-acc = 224 regs -> 2 waves/SIMD (ok).
// Column layout (inner 1024): c = dir*512 + 2*p + comp  (comp: 0=re, 1=im)
// LDS tiles use XOR swizzle (T2): linear global_load_lds dest, pre-swizzled
// global source column, XOR'd ds_read index (rule #21). R2: conflicts == 0.
// ---------------------------------------------------------------------------

typedef short bf16x8 __attribute__((ext_vector_type(8)));
typedef float f32x4 __attribute__((ext_vector_type(4)));
typedef unsigned short u16x8 __attribute__((ext_vector_type(8)));

__device__ __forceinline__ unsigned short f2bf(float f) {
  union { float f; unsigned int u; } v; v.f = f;
  unsigned int r = (v.u + 0x7FFFu + ((v.u >> 16) & 1u)) >> 16;
  return (unsigned short)r;
}
__device__ __forceinline__ float bf2f(unsigned short s) {
  union { unsigned int u; float f; } v; v.u = ((unsigned int)s) << 16;
  return v.f;
}
// tanh-form gelu via sigmoid: gelu(v) ~= v * sigmoid(1.5957691*(v+0.044715 v^3))
// max abs deviation from exact erf-gelu ~3e-4 (well under threshold headroom).
__device__ __forceinline__ float gelu_fast(float v) {
  const float u = 1.5957691216057308f * fmaf(0.044715f * v, v * v, v);
  return v / (1.f + __expf(-u));
}
__device__ __forceinline__ void gload16(const unsigned short* g, void* l) {
  __builtin_amdgcn_global_load_lds(
      (const __attribute__((address_space(1))) void*)g,
      (__attribute__((address_space(3))) void*)l, 16, 0, 0);
}

// ------------------------------- cast x -> bf16 ----------------------------
__global__ __launch_bounds__(256) void cast_x_kernel(
    const float* __restrict__ x, unsigned short* __restrict__ xbf) {
  const size_t i = (size_t)blockIdx.x * 256 + threadIdx.x;  // 2,097,152 total
  const float4* xv = (const float4*)x;
  float4 a = xv[2 * i], b = xv[2 * i + 1];
  u16x8 r;
  r[0] = f2bf(a.x); r[1] = f2bf(a.y); r[2] = f2bf(a.z); r[3] = f2bf(a.w);
  r[4] = f2bf(b.x); r[5] = f2bf(b.y); r[6] = f2bf(b.z); r[7] = f2bf(b.w);
  *(u16x8*)(xbf + 8 * i) = r;
}

// ------------------------------- prep ---------------------------------------
__global__ __launch_bounds__(256) void prep_kernel(
    const float* __restrict__ flr, const float* __restrict__ fim,
    const float* __restrict__ fBr, const float* __restrict__ fBi,
    const float* __restrict__ fCr, const float* __restrict__ fCi,
    const float* __restrict__ flD,
    const float* __restrict__ blr, const float* __restrict__ bim,
    const float* __restrict__ bBr, const float* __restrict__ bBi,
    const float* __restrict__ bCr, const float* __restrict__ bCi,
    const float* __restrict__ blD,
    unsigned short* __restrict__ W, unsigned short* __restrict__ CmT,
    float4* __restrict__ lamp) {
  const int bid = blockIdx.x, tid = threadIdx.x;
  if (bid < 512) {
    const int dir = bid >> 8, p = bid & 255;
    const float* lr_ = dir ? blr : flr;
    const float* im_ = dir ? bim : fim;
    const float* lD_ = dir ? blD : flD;
    const float* Br_ = dir ? bBr : fBr;
    const float* Bi_ = dir ? bBi : fBi;
    const float Lre = -expf(lr_[p]);
    const float Lim = im_[p];
    const float Dl = expf(lD_[p]);
    const float ar = Lre * Dl, ai = Lim * Dl;
    const float er = expf(ar);
    const float lre = er * cosf(ai), lim = er * sinf(ai);
    const float e64 = expf(64.f * ar);
    const float l64re = e64 * cosf(64.f * ai), l64im = e64 * sinf(64.f * ai);
    float sre = Lre, sim = Lim;
    if (sqrtf(Lre * Lre + Lim * Lim) < 1e-6f) { sre = 1e-6f; sim = 0.f; }
    const float den = sre * sre + sim * sim;
    const float fre = ((lre - 1.f) * sre + lim * sim) / den;
    const float fi2 = (lim * sre - (lre - 1.f) * sim) / den;
    if (tid == 0) lamp[dir * 256 + p] = make_float4(lre, lim, l64re, l64im);
    const size_t rowR = (size_t)(dir * 512 + 2 * p) * 1024;
    const size_t rowI = rowR + 1024;
    for (int h = tid; h < 1024; h += 256) {
      const float Br = Br_[p * 1024 + h], Bi = Bi_[p * 1024 + h];
      W[rowR + h] = f2bf(fre * Br - fi2 * Bi);
      W[rowI + h] = f2bf(fre * Bi + fi2 * Br);
    }
  } else {
    const int h = bid - 512;
    for (int k = tid; k < 1024; k += 256) {
      const int dir = k >> 9, within = k & 511;
      const int p = within >> 1, comp = within & 1;
      const float* C = comp ? (dir ? bCi : fCi) : (dir ? bCr : fCr);
      float v = C[(size_t)h * 256 + p];
      if (comp) v = -v;
      CmT[(size_t)h * 1024 + k] = f2bf(v);
    }
  }
}

// --------------------- shared 128x128-tile K-step macro ---------------------
// Stages A-tile rows m0..m0+127, B-tile rows n0..n0+127 (64 K-cols) and does
// 32 MFMAs per wave (4x4 frags x 2 kk).  Needs: tid, tr, csw, m0, n0, wm, wn,
// fr, ks, sw, As, Bs in scope.
#define GEMM_KSTEP(ACC, KT, APTR, BPTR)                                        \
  {                                                                            \
    const int k0 = (KT) << 6;                                                  \
    _Pragma("unroll") for (int i = 0; i < 4; ++i) {                            \
      const int r = (i << 5) + tr;                                             \
      const int o = (i << 12) + (tid << 4);                                    \
      gload16(APTR + (size_t)(m0 + r) * 1024 + (k0 + csw), (char*)As + o);     \
      gload16(BPTR + (size_t)(n0 + r) * 1024 + (k0 + csw), (char*)Bs + o);     \
    }                                                                          \
    __syncthreads();                                                           \
    _Pragma("unroll") for (int kk = 0; kk < 64; kk += 32) {                    \
      bf16x8 af[4], bf_[4];                                                    \
      _Pragma("unroll") for (int m4 = 0; m4 < 4; ++m4) {                       \
        const int row = (wm << 6) + (m4 << 4) + fr;                            \
        af[m4] = *(const bf16x8*)&As[row * 64 + ((kk + ks) ^ sw)];             \
      }                                                                        \
      _Pragma("unroll") for (int n4 = 0; n4 < 4; ++n4) {                       \
        const int row = (wn << 6) + (n4 << 4) + fr;                            \
        bf_[n4] = *(const bf16x8*)&Bs[row * 64 + ((kk + ks) ^ sw)];            \
      }                                                                        \
      _Pragma("unroll") for (int m4 = 0; m4 < 4; ++m4)                         \
          _Pragma("unroll") for (int n4 = 0; n4 < 4; ++n4)                     \
              ACC[m4][n4] = __builtin_amdgcn_mfma_f32_16x16x32_bf16(           \
                  af[m4], bf_[n4], ACC[m4][n4], 0, 0, 0);                      \
    }                                                                          \
    __syncthreads();                                                           \
  }

// ------------------------------- GEMM1 --------------------------------------
// Zb[m][c] = bf16( sum_h xbf[m][h] * W[c][h] );  M=16384, N=1024, K=1024
__global__ __launch_bounds__(256) void gemm1_kernel(
    const unsigned short* __restrict__ xbf, const unsigned short* __restrict__ W,
    unsigned short* __restrict__ Zb) {
  __shared__ unsigned short As[128 * 64];
  __shared__ unsigned short Bs[128 * 64];
  const int tid = threadIdx.x;
  const int lane = tid & 63;
  const int w = tid >> 6;
  const int wm = w >> 1, wn = w & 1;
  const int fr = lane & 15;
  const int ks = (lane >> 4) << 3;
  const int sw = (fr & 7) << 3;                     // ds_read XOR (elements)
  const int tr = tid >> 3;                          // staging row-within-32
  const int csw = ((tid & 7) ^ (tr & 7)) << 3;      // staging src col (elems)
  const int bsw = ((blockIdx.x & 7) << 7) + (blockIdx.x >> 3);  // XCD swizzle
  const int nt = bsw & 7, mt = bsw >> 3;
  const int m0 = mt << 7, n0 = nt << 7;

  f32x4 acc[4][4] = {};

  for (int kt = 0; kt < 16; ++kt) GEMM_KSTEP(acc, kt, xbf, W);

  const int rb = (lane >> 4) << 2;
#pragma unroll
  for (int m4 = 0; m4 < 4; ++m4)
#pragma unroll
    for (int n4 = 0; n4 < 4; ++n4) {
      const size_t gn = n0 + (wn << 6) + (n4 << 4) + fr;
#pragma unroll
      for (int r = 0; r < 4; ++r) {
        const size_t gm = m0 + (wm << 6) + (m4 << 4) + rb + r;
        Zb[gm * 1024 + gn] = f2bf(acc[m4][n4][r]);
      }
    }
}

// ------------------------------- scans --------------------------------------
// Zb viewed as u32 pairs: Zp[m][512], col = dir*256 + p, packed (re, im) bf16.
__global__ __launch_bounds__(256) void scanA_kernel(
    unsigned int* __restrict__ Zp, const float4* __restrict__ lamp,
    float2* __restrict__ partials) {
  const int p = threadIdx.x;
  const int chunk = blockIdx.x & 63;
  const int dir = (blockIdx.x >> 6) & 1;
  const int b = blockIdx.x >> 7;
  const float4 lp = lamp[dir * 256 + p];
  const float lre = lp.x, lim = lp.y;
  const size_t col = (size_t)dir * 256 + p;
  const size_t mbase = (size_t)b * 4096 + (size_t)chunk * 64;
  float sre = 0.f, sim = 0.f;
  if (dir == 0) {
    for (int i = 0; i < 64; ++i) {
      const size_t idx = (mbase + i) * 512 + col;
      const unsigned int u = Zp[idx];
      const float ur = bf2f((unsigned short)u), ui = bf2f((unsigned short)(u >> 16));
      const float nr = fmaf(lre, sre, fmaf(-lim, sim, ur));
      const float ni = fmaf(lre, sim, fmaf(lim, sre, ui));
      sre = nr; sim = ni;
      Zp[idx] = (unsigned int)f2bf(sre) | ((unsigned int)f2bf(sim) << 16);
    }
  } else {
    for (int i = 63; i >= 0; --i) {
      const size_t idx = (mbase + i) * 512 + col;
      const unsigned int u = Zp[idx];
      const float ur = bf2f((unsigned short)u), ui = bf2f((unsigned short)(u >> 16));
      const float nr = fmaf(lre, sre, fmaf(-lim, sim, ur));
      const float ni = fmaf(lre, sim, fmaf(lim, sre, ui));
      sre = nr; sim = ni;
      Zp[idx] = (unsigned int)f2bf(sre) | ((unsigned int)f2bf(sim) << 16);
    }
  }
  partials[((size_t)(b * 2 + dir) * 256 + p) * 64 + chunk] = make_float2(sre, sim);
}

__global__ __launch_bounds__(256) void scanB_kernel(
    const float2* __restrict__ partials, float2* __restrict__ carries,
    const float4* __restrict__ lamp) {
  const int t = blockIdx.x * 256 + threadIdx.x;  // < 2048
  const int p = t & 255;
  const int dir = (t >> 8) & 1;
  const int b = t >> 9;
  const float4 lp = lamp[dir * 256 + p];
  const float ar = lp.z, ai = lp.w;  // lambda^64
  const size_t base = ((size_t)(b * 2 + dir) * 256 + p) * 64;
  float cr = 0.f, ci = 0.f;
  if (dir == 0) {
    for (int c = 0; c < 64; ++c) {
      carries[base + c] = make_float2(cr, ci);
      float2 s = partials[base + c];
      float nr = fmaf(ar, cr, fmaf(-ai, ci, s.x));
      float ni = fmaf(ar, ci, fmaf(ai, cr, s.y));
      cr = nr; ci = ni;
    }
  } else {
    for (int c = 63; c >= 0; --c) {
      carries[base + c] = make_float2(cr, ci);
      float2 s = partials[base + c];
      float nr = fmaf(ar, cr, fmaf(-ai, ci, s.x));
      float ni = fmaf(ar, ci, fmaf(ai, cr, s.y));
      cr = nr; ci = ni;
    }
  }
}

__global__ __launch_bounds__(256) void scanC_kernel(
    const unsigned int* __restrict__ Zp, const float4* __restrict__ lamp,
    const float2* __restrict__ carries, unsigned int* __restrict__ xsbf) {
  const int p = threadIdx.x;
  const int chunk = blockIdx.x & 63;
  const int dir = (blockIdx.x >> 6) & 1;
  const int b = blockIdx.x >> 7;
  const float4 lp = lamp[dir * 256 + p];
  const float lre = lp.x, lim = lp.y;
  const size_t col = (size_t)dir * 256 + p;
  const size_t mbase = (size_t)b * 4096 + (size_t)chunk * 64;
  const float2 K = carries[((size_t)(b * 2 + dir) * 256 + p) * 64 + chunk];
  float qr = lre * K.x - lim * K.y;
  float qi = lre * K.y + lim * K.x;
  if (dir == 0) {
    for (int i = 0; i < 64; ++i) {
      const size_t idx = (mbase + i) * 512 + col;
      const unsigned int u = Zp[idx];
      const float vr = bf2f((unsigned short)u) + qr;
      const float vi = bf2f((unsigned short)(u >> 16)) + qi;
      xsbf[idx] = (unsigned int)f2bf(vr) | ((unsigned int)f2bf(vi) << 16);
      const float t2 = lre * qr - lim * qi;
      qi = lre * qi + lim * qr; qr = t2;
    }
  } else {
    for (int i = 63; i >= 0; --i) {
      const size_t idx = (mbase + i) * 512 + col;
      const unsigned int u = Zp[idx];
      const float vr = bf2f((unsigned short)u) + qr;
      const float vi = bf2f((unsigned short)(u >> 16)) + qi;
      xsbf[idx] = (unsigned int)f2bf(vr) | ((unsigned int)f2bf(vi) << 16);
      const float t2 = lre * qr - lim * qi;
      qi = lre * qi + lim * qr; qr = t2;
    }
  }
}

// ------------------------------- GEMM2 + epilogue ---------------------------
// 128x128 tile, per-wave 64x64, dual acc: accf over kt 0..7 (K 0..511, fwd),
// accb over kt 8..15 (K 512..1023, bwd).
// out = gelu(acc_f + Df*x) + gelu(acc_b + Db*x)
__global__ __launch_bounds__(256, 2) void gemm2_kernel(
    const unsigned short* __restrict__ A2, const unsigned short* __restrict__ CmT,
    const unsigned short* __restrict__ xbf, const float* __restrict__ Df,
    const float* __restrict__ Db, float* __restrict__ out) {
  __shared__ unsigned short As[128 * 64];
  __shared__ unsigned short Bs[128 * 64];
  const int tid = threadIdx.x;
  const int lane = tid & 63;
  const int w = tid >> 6;
  const int wm = w >> 1, wn = w & 1;
  const int fr = lane & 15;
  const int ks = (lane >> 4) << 3;
  const int sw = (fr & 7) << 3;
  const int tr = tid >> 3;
  const int csw = ((tid & 7) ^ (tr & 7)) << 3;
  const int bsw = ((blockIdx.x & 7) << 7) + (blockIdx.x >> 3);  // XCD swizzle
  const int nt = bsw & 7, mt = bsw >> 3;
  const int m0 = mt << 7, n0 = nt << 7;

  f32x4 accf[4][4] = {};
  f32x4 accb[4][4] = {};

  for (int kt = 0; kt < 8; ++kt) GEMM_KSTEP(accf, kt, A2, CmT);
  for (int kt = 8; kt < 16; ++kt) GEMM_KSTEP(accb, kt, A2, CmT);

  const int rb = (lane >> 4) << 2;
#pragma unroll
  for (int n4 = 0; n4 < 4; ++n4) {
    const size_t gn = n0 + (wn << 6) + (n4 << 4) + fr;
    const float dfv = Df[gn], dbv = Db[gn];
#pragma unroll
    for (int m4 = 0; m4 < 4; ++m4) {
#pragma unroll
      for (int r = 0; r < 4; ++r) {
        const size_t gm = m0 + (wm << 6) + (m4 << 4) + rb + r;
        const float xv = bf2f(xbf[gm * 1024 + gn]);
        out[gm * 1024 + gn] = gelu_fast(accf[m4][n4][r] + dfv * xv) +
                              gelu_fast(accb[m4][n4][r] + dbv * xv);
      }
    }
  }
}

// ------------------------------- launch -------------------------------------
extern "C" void kernel_launch(void* const* d_in, const int* in_sizes, int n_in,
                              void* d_out, int out_size, void* d_ws, size_t ws_size,
                              hipStream_t stream) {
  const float* x = (const float*)d_in[0];
  const float* flr = (const float*)d_in[1];
  const float* fim = (const float*)d_in[2];
  const float* fBr = (const float*)d_in[3];
  const float* fBi = (const float*)d_in[4];
  const float* fCr = (const float*)d_in[5];
  const float* fCi = (const float*)d_in[6];
  const float* fD  = (const float*)d_in[7];
  const float* flD = (const float*)d_in[8];
  const float* blr = (const float*)d_in[9];
  const float* bim = (const float*)d_in[10];
  const float* bBr = (const float*)d_in[11];
  const float* bBi = (const float*)d_in[12];
  const float* bCr = (const float*)d_in[13];
  const float* bCi = (const float*)d_in[14];
  const float* bD  = (const float*)d_in[15];
  const float* blD = (const float*)d_in[16];

  char* ws = (char*)d_ws;
  unsigned short* xbf  = (unsigned short*)(ws);                  // 33,554,432
  unsigned short* W    = (unsigned short*)(ws + 33554432);       //  2,097,152
  unsigned short* CmT  = (unsigned short*)(ws + 35651584);       //  2,097,152
  unsigned short* Zb   = (unsigned short*)(ws + 37748736);       // 33,554,432
  unsigned short* xsbf = (unsigned short*)(ws + 71303168);       // 33,554,432
  float4*         lamp = (float4*)(ws + 104857600);              //      8,192
  float2*         part = (float2*)(ws + 104865792);              //  1,048,576
  float2*         carr = (float2*)(ws + 105914368);              //  1,048,576

  dim3 blk(256);
  cast_x_kernel<<<8192, blk, 0, stream>>>(x, xbf);
  prep_kernel<<<1536, blk, 0, stream>>>(flr, fim, fBr, fBi, fCr, fCi, flD,
                                        blr, bim, bBr, bBi, bCr, bCi, blD,
                                        W, CmT, lamp);
  gemm1_kernel<<<1024, blk, 0, stream>>>(xbf, W, Zb);
  scanA_kernel<<<512, blk, 0, stream>>>((unsigned int*)Zb, lamp, part);
  scanB_kernel<<<8, blk, 0, stream>>>(part, carr, lamp);
  scanC_kernel<<<512, blk, 0, stream>>>((unsigned int*)Zb, lamp, carr,
                                        (unsigned int*)xsbf);
  gemm2_kernel<<<1024, blk, 0, stream>>>(xsbf, CmT, xbf, fD, bD, (float*)d_out);
}